// Round 2
// baseline (562.961 us; speedup 1.0000x reference)
//
#include <hip/hip_runtime.h>

// Model: e = maxpool_L(relu(x @ Wc^T + bc)); feat = [e1-e2, e1*e2];
//        h = tanh(feat @ W1^T + b1); out = h @ W2^T + b2   (all fp32 I/O)
// Sizes: B=2048, L=64, D=300, C=512, H=2048, O=1.
// R4: LDS-staged encode 232us; R5: direct-global encode 262us. Both latency-
//   bound at ~12% HBM: short-lived blocks, serial stage->barrier->compute,
//   ~2 waves/SIMD. Encode staging:compute cycle ratio is ~5:1 -> it is an
//   HBM STREAMING problem.
// R6: persistent encode. 256 blocks x 512 thr (1/CU), each streams 16 tiles
//   (8 b x 2 inputs) with double-buffered LDS; T14 async-stage split (issue
//   ~10 dwordx4/thread at iter top, cvt+ds_write after the compute barrier)
//   keeps ~77KB/CU of HBM loads in flight. LDS layout = fragment-sequential
//   (same formula as WcSwz) so every ds_read/ds_write is a linear 1KB wave
//   op (0 bank conflicts). feat fused into encode epilogue (e1 held in regs,
//   featSwz written directly); finalize fused into fc1 via atomicAdd.

#define B_SZ 2048
#define L_SZ 64
#define D_SZ 300
#define C_SZ 512
#define H_SZ 2048
#define NKC 40        // K-chunks (8 bf16) per row, K padded 300->320

typedef __bf16 bf16x8 __attribute__((ext_vector_type(8)));
typedef float f32x4 __attribute__((ext_vector_type(4)));

__device__ __forceinline__ unsigned short f2bf(float f) {
  unsigned int u = __float_as_uint(f);
  u += 0x7fffu + ((u >> 16) & 1u);   // RNE
  return (unsigned short)(u >> 16);
}

// ---- kernel 0: build swizzled bf16 weights + init out = b2.
// WcSwz[(c/16)*40 + kc][l16=c%16][8]  (zero-pad k>=300)
// W1Swz[(j/16)*128 + kc][l16=j%16][8]
__global__ __launch_bounds__(256)
void convert_kernel(const float* __restrict__ Wc, const float* __restrict__ W1,
                    const float* __restrict__ b2,
                    unsigned short* __restrict__ WcSwz, unsigned short* __restrict__ W1Swz,
                    float* __restrict__ out) {
  int id = blockIdx.x * 256 + threadIdx.x;
  if (id < B_SZ) out[id] = b2[0];             // fc1 accumulates into out
  if (id < C_SZ * NKC) {                      // 20480 threads: (c, kc)
    int c = id / NKC, kc = id - c * NKC;
    unsigned short tmp[8];
    #pragma unroll
    for (int i = 0; i < 8; ++i) {
      int k = kc * 8 + i;
      tmp[i] = (k < D_SZ) ? f2bf(Wc[c * D_SZ + k]) : (unsigned short)0;
    }
    unsigned short* dst = WcSwz + (((c >> 4) * NKC + kc) * 16 + (c & 15)) * 8;
    *reinterpret_cast<uint4*>(dst) = *reinterpret_cast<uint4*>(tmp);
    return;
  }
  id -= C_SZ * NKC;
  if (id < H_SZ * 128) {                      // 262144 threads: (j, kc)
    int j = id >> 7, kc = id & 127;
    const float* src = W1 + (size_t)j * 1024 + kc * 8;
    unsigned short tmp[8];
    #pragma unroll
    for (int i = 0; i < 8; ++i) tmp[i] = f2bf(src[i]);
    unsigned short* dst = W1Swz + (((j >> 4) * 128 + kc) * 16 + (j & 15)) * 8;
    *reinterpret_cast<uint4*>(dst) = *reinterpret_cast<uint4*>(tmp);
  }
}

// ---- kernel 1: persistent encode + feat. 256 blocks (1/CU), 512 threads.
// Block handles b = bid + 256*i, i<8; per b two tiles (z=0,1), 16 tiles total,
// double-buffered. Wave w covers channels [w*64, w*64+64).
__global__ __launch_bounds__(512, 2)
void encode_feat_kernel(const float* __restrict__ x1, const float* __restrict__ x2,
                        const unsigned short* __restrict__ WcSwz,
                        const float* __restrict__ bc,
                        unsigned short* __restrict__ featSwz) {
  __shared__ unsigned short xs[2][64 * NKC * 8];   // 2 x 40960 B, fragment-sequential
  __shared__ float fs[1024];                       // feat scratch (diff | prod)
  const int tid = threadIdx.x;
  const int wave = tid >> 6, lane = tid & 63;
  const int l16 = lane & 15, quad = lane >> 4;

  // zero pad chunks kc=38,39 (k>=304) once; kc=37 high half is zeroed per-stage.
  for (int i = tid; i < 256; i += 512) {
    int buf = i >> 7, r = i & 127;
    int mt = r >> 5, kc = 38 + ((r >> 4) & 1), l = r & 15;
    *reinterpret_cast<uint4*>(&xs[buf][mt * 5120 + kc * 128 + l * 8]) = make_uint4(0, 0, 0, 0);
  }

  float bias[4];
  #pragma unroll
  for (int nt = 0; nt < 4; ++nt) bias[nt] = bc[wave * 64 + nt * 16 + l16];

  // staging: 2432 items = (4 mt x 38 c8) x 16 l; item = 32B of one row
  float4 pf0[5], pf1[5];
  auto LOAD = [&](int t) {
    const float* xb = ((t & 1) ? x2 : x1) +
                      (size_t)(blockIdx.x + (t >> 1) * 256) * (L_SZ * D_SZ);
    #pragma unroll
    for (int r = 0; r < 5; ++r) {
      int idx = r * 512 + tid;
      if (idx < 2432) {
        int g = idx >> 4, l = idx & 15;
        int mt = g / 38, c8 = g - mt * 38;
        const float* s = xb + (mt * 16 + l) * D_SZ + c8 * 8;
        pf0[r] = *reinterpret_cast<const float4*>(s);
        pf1[r] = (c8 < 37) ? *reinterpret_cast<const float4*>(s + 4)
                           : make_float4(0.f, 0.f, 0.f, 0.f);
      }
    }
  };
  auto WRITE = [&](int buf) {
    #pragma unroll
    for (int r = 0; r < 5; ++r) {
      int idx = r * 512 + tid;
      if (idx < 2432) {
        int g = idx >> 4, l = idx & 15;
        int mt = g / 38, c8 = g - mt * 38;
        unsigned int w0 = (unsigned int)f2bf(pf0[r].x) | ((unsigned int)f2bf(pf0[r].y) << 16);
        unsigned int w1 = (unsigned int)f2bf(pf0[r].z) | ((unsigned int)f2bf(pf0[r].w) << 16);
        unsigned int w2 = (unsigned int)f2bf(pf1[r].x) | ((unsigned int)f2bf(pf1[r].y) << 16);
        unsigned int w3 = (unsigned int)f2bf(pf1[r].z) | ((unsigned int)f2bf(pf1[r].w) << 16);
        *reinterpret_cast<uint4*>(&xs[buf][mt * 5120 + c8 * 128 + l * 8]) =
            make_uint4(w0, w1, w2, w3);
      }
    }
  };

  LOAD(0);
  WRITE(0);
  __syncthreads();

  const unsigned short* wc_lane = WcSwz + (wave * 4) * 5120 + quad * 128 + l16 * 8;
  float e1[4];
  int cur = 0;

  #pragma unroll 2
  for (int t = 0; t < 16; ++t) {
    if (t < 15) LOAD(t + 1);               // issue next tile's HBM loads early

    f32x4 acc[4][4];
    #pragma unroll
    for (int mt = 0; mt < 4; ++mt)
      #pragma unroll
      for (int nt = 0; nt < 4; ++nt)
        #pragma unroll
        for (int r = 0; r < 4; ++r) acc[mt][nt][r] = 0.f;

    const unsigned short* xb = &xs[cur][quad * 128 + l16 * 8];
    #pragma unroll
    for (int ks = 0; ks < 10; ++ks) {
      bf16x8 a[4];
      #pragma unroll
      for (int mt = 0; mt < 4; ++mt)
        a[mt] = *reinterpret_cast<const bf16x8*>(xb + mt * 5120 + ks * 512);
      #pragma unroll
      for (int nt = 0; nt < 4; ++nt) {
        bf16x8 bw = *reinterpret_cast<const bf16x8*>(wc_lane + nt * 5120 + ks * 512);
        #pragma unroll
        for (int mt = 0; mt < 4; ++mt)
          acc[mt][nt] = __builtin_amdgcn_mfma_f32_16x16x32_bf16(a[mt], bw, acc[mt][nt], 0, 0, 0);
      }
    }

    // epilogue: +bias, relu, max over 64 words (D row = quad*4+r, col = l16)
    #pragma unroll
    for (int nt = 0; nt < 4; ++nt) {
      float v = 0.f;
      #pragma unroll
      for (int mt = 0; mt < 4; ++mt)
        #pragma unroll
        for (int r = 0; r < 4; ++r)
          v = fmaxf(v, acc[mt][nt][r] + bias[nt]);
      v = fmaxf(v, __shfl_xor(v, 16));
      v = fmaxf(v, __shfl_xor(v, 32));
      if (!(t & 1)) {
        e1[nt] = v;
      } else if (quad == 0) {
        int c = wave * 64 + nt * 16 + l16;
        fs[c]       = e1[nt] - v;
        fs[512 + c] = e1[nt] * v;
      }
    }

    __syncthreads();   // xs[cur] reads done; fs visible

    if (t & 1) {       // pack feat for this b into featSwz
      int b = blockIdx.x + (t >> 1) * 256;
      if (tid < 128) {
        unsigned short tmp[8];
        #pragma unroll
        for (int i = 0; i < 8; ++i) tmp[i] = f2bf(fs[tid * 8 + i]);
        *reinterpret_cast<uint4*>(featSwz + (((b >> 4) * 128 + tid) * 16 + (b & 15)) * 8) =
            *reinterpret_cast<uint4*>(tmp);
      }
    }
    if (t < 15) WRITE(cur ^ 1);            // vmcnt wait + cvt + ds_write late

    __syncthreads();   // xs[cur^1] writes + fs reads complete
    cur ^= 1;
  }
}

// ---- kernel 2: fc1+fc2 fused. pre = feat @ W1^T + b1; t = tanh(pre);
// out[b] += sum over this wave's 32 j-cols of t * W2[j]  (atomic).
__global__ __launch_bounds__(256, 4)
void fc1_kernel(const unsigned short* __restrict__ featSwz,
                const unsigned short* __restrict__ W1Swz,
                const float* __restrict__ b1, const float* __restrict__ W2,
                float* __restrict__ out) {
  const int mbase = blockIdx.x * 32;
  const int tid = threadIdx.x;
  const int wave = tid >> 6, lane = tid & 63;
  const int l16 = lane & 15, quad = lane >> 4;
  const int nbase = blockIdx.y * 128 + wave * 32;

  f32x4 acc[2][2];
  #pragma unroll
  for (int mt = 0; mt < 2; ++mt)
    #pragma unroll
    for (int nt = 0; nt < 2; ++nt)
      #pragma unroll
      for (int r = 0; r < 4; ++r) acc[mt][nt][r] = 0.f;

  #pragma unroll 4
  for (int ks = 0; ks < 32; ++ks) {
    bf16x8 a[2], bw[2];
    #pragma unroll
    for (int mt = 0; mt < 2; ++mt)
      a[mt] = *reinterpret_cast<const bf16x8*>(
          featSwz + (((size_t)(blockIdx.x * 2 + mt) * 128 + ks * 4 + quad) * 16 + l16) * 8);
    #pragma unroll
    for (int nt = 0; nt < 2; ++nt)
      bw[nt] = *reinterpret_cast<const bf16x8*>(
          W1Swz + (((size_t)(blockIdx.y * 8 + wave * 2 + nt) * 128 + ks * 4 + quad) * 16 + l16) * 8);
    #pragma unroll
    for (int mt = 0; mt < 2; ++mt)
      #pragma unroll
      for (int nt = 0; nt < 2; ++nt)
        acc[mt][nt] = __builtin_amdgcn_mfma_f32_16x16x32_bf16(a[mt], bw[nt], acc[mt][nt], 0, 0, 0);
  }

  // epilogue: tanh in fp32, dot with W2, reduce over this wave's 32 j-cols
  float c[2][4];
  #pragma unroll
  for (int mt = 0; mt < 2; ++mt)
    #pragma unroll
    for (int r = 0; r < 4; ++r) c[mt][r] = 0.f;

  #pragma unroll
  for (int nt = 0; nt < 2; ++nt) {
    int j = nbase + nt * 16 + l16;
    float bias = b1[j];
    float w2 = W2[j];
    #pragma unroll
    for (int mt = 0; mt < 2; ++mt)
      #pragma unroll
      for (int r = 0; r < 4; ++r) {
        float pre = acc[mt][nt][r] + bias;
        pre = fminf(fmaxf(pre, -15.f), 15.f);
        float ex = __expf(2.f * pre);
        c[mt][r] += w2 * ((ex - 1.f) / (ex + 1.f));
      }
  }
  #pragma unroll
  for (int off = 1; off <= 8; off <<= 1)
    #pragma unroll
    for (int mt = 0; mt < 2; ++mt)
      #pragma unroll
      for (int r = 0; r < 4; ++r)
        c[mt][r] += __shfl_xor(c[mt][r], off);

  if (l16 == 0) {
    #pragma unroll
    for (int mt = 0; mt < 2; ++mt)
      #pragma unroll
      for (int r = 0; r < 4; ++r) {
        int brow = mbase + mt * 16 + quad * 4 + r;
        atomicAdd(&out[brow], c[mt][r]);
      }
  }
}

extern "C" void kernel_launch(void* const* d_in, const int* in_sizes, int n_in,
                              void* d_out, int out_size, void* d_ws, size_t ws_size,
                              hipStream_t stream) {
  const float* x1 = (const float*)d_in[0];
  const float* x2 = (const float*)d_in[1];
  const float* Wc = (const float*)d_in[2];
  const float* bc = (const float*)d_in[3];
  const float* W1 = (const float*)d_in[4];
  const float* b1 = (const float*)d_in[5];
  const float* W2 = (const float*)d_in[6];
  const float* b2 = (const float*)d_in[7];

  char* ws = (char*)d_ws;
  unsigned short* WcSwz   = (unsigned short*)(ws);             // 327,680 B
  unsigned short* W1Swz   = (unsigned short*)(ws + 327680);    // 4,194,304 B
  unsigned short* featSwz = (unsigned short*)(ws + 4521984);   // 4,194,304 B
  // total: 8,716,288 B

  {
    int total = C_SZ * NKC + H_SZ * 128;  // 282,624
    convert_kernel<<<(total + 255) / 256, 256, 0, stream>>>(Wc, W1, b2, WcSwz, W1Swz,
                                                            (float*)d_out);
  }
  encode_feat_kernel<<<256, 512, 0, stream>>>(x1, x2, WcSwz, bc, featSwz);
  fc1_kernel<<<dim3(B_SZ / 32, H_SZ / 128), 256, 0, stream>>>(featSwz, W1Swz, b1, W2,
                                                              (float*)d_out);
}